// Round 3
// baseline (1384.255 us; speedup 1.0000x reference)
//
#include <hip/hip_runtime.h>
#include <math.h>

#define N_NODES 100000
#define N_EDGES 3200000
#define IN_CH 256
#define NC 20        // combined output channels (10 mu + 10 logstd)
#define OC 10
#define BNODES 128   // nodes per bucket (col >> 7)
#define NBUCK 782    // ceil(100000/128)
#define ASTRIDE 21   // LDS acc stride: coprime with 32 banks (20 would be 8-way conflict)

// ---------- coarse histogram over buckets (LDS-staged) ----------
__global__ __launch_bounds__(256) void k_chist(const int* __restrict__ col,
                                               int* __restrict__ bcnt) {
    __shared__ int lh[NBUCK];
    for (int i = threadIdx.x; i < NBUCK; i += 256) lh[i] = 0;
    __syncthreads();
    int stride = gridDim.x * 256;
    for (int e = blockIdx.x * 256 + threadIdx.x; e < N_EDGES; e += stride)
        atomicAdd(&lh[col[e] >> 7], 1);
    __syncthreads();
    for (int i = threadIdx.x; i < NBUCK; i += 256) {
        int v = lh[i];
        if (v) atomicAdd(&bcnt[i], v);
    }
}

// ---------- exclusive scan of 782 bucket counts (single block) ----------
__global__ __launch_bounds__(1024) void k_scan(const int* __restrict__ bcnt,
                                               int* __restrict__ boff,
                                               int* __restrict__ bptr) {
    __shared__ int s[1024];
    int t = threadIdx.x;
    int v = (t < NBUCK) ? bcnt[t] : 0;
    s[t] = v;
    __syncthreads();
    for (int off = 1; off < 1024; off <<= 1) {
        int tv = (t >= off) ? s[t - off] : 0;
        __syncthreads();
        s[t] += tv;
        __syncthreads();
    }
    if (t < NBUCK) { boff[t] = s[t] - v; bptr[t] = s[t] - v; }
}

// ---------- bin edges into bucket regions; pack (row<<7)|(col&127) ----------
__global__ __launch_bounds__(256) void k_bin(const int* __restrict__ row,
                                             const int* __restrict__ col,
                                             int* __restrict__ bptr,
                                             int* __restrict__ bpairs) {
    int e = blockIdx.x * 256 + threadIdx.x;
    if (e >= N_EDGES) return;
    int r = row[e], c = col[e];
    int slot = atomicAdd(&bptr[c >> 7], 1);
    bpairs[slot] = (r << 7) | (c & 127);
}

// ---------- per-node degree via LDS counts; dinv = rsqrt(deg+1) ----------
__global__ __launch_bounds__(256) void k_bcount(const int* __restrict__ boff,
                                                const int* __restrict__ bcnt,
                                                const int* __restrict__ bpairs,
                                                float* __restrict__ dinv) {
    __shared__ int lc[BNODES];
    int b = blockIdx.x, t = threadIdx.x;
    if (t < BNODES) lc[t] = 0;
    __syncthreads();
    int start = boff[b], n = bcnt[b];
    for (int p = t; p < n; p += 256)
        atomicAdd(&lc[bpairs[start + p] & 127], 1);
    __syncthreads();
    int node = b * BNODES + t;
    if (t < BNODES && node < N_NODES)
        dinv[node] = rsqrtf((float)(lc[t] + 1));  // +1 self loop
}

// ---------- fused skinny GEMM: h[N][20] = x @ [W_mu | W_logstd] ----------
__global__ __launch_bounds__(256) void k_gemm(const float* __restrict__ x,
                                              const float* __restrict__ Wmu,
                                              const float* __restrict__ Wls,
                                              float* __restrict__ h) {
    __shared__ float sW[IN_CH * NC];
    int tid = threadIdx.x;
    for (int j = tid; j < IN_CH * OC; j += 256) {
        int k = j / OC, c = j - k * OC;
        sW[k * NC + c]      = Wmu[j];
        sW[k * NC + OC + c] = Wls[j];
    }
    __syncthreads();
    int node = blockIdx.x * 256 + tid;
    if (node >= N_NODES) return;

    const float4* x4 = (const float4*)(x + (size_t)node * IN_CH);
    float acc[NC];
#pragma unroll
    for (int c = 0; c < NC; c++) acc[c] = 0.0f;

#pragma unroll 4
    for (int k4 = 0; k4 < IN_CH / 4; k4++) {
        float4 xv = x4[k4];
        const float* w0 = &sW[(k4 * 4 + 0) * NC];
        const float* w1 = w0 + NC;
        const float* w2 = w1 + NC;
        const float* w3 = w2 + NC;
#pragma unroll
        for (int c = 0; c < NC; c++)
            acc[c] += xv.x * w0[c] + xv.y * w1[c] + xv.z * w2[c] + xv.w * w3[c];
    }

    float4* hp = (float4*)(h + (size_t)node * NC);
    hp[0] = make_float4(acc[0],  acc[1],  acc[2],  acc[3]);
    hp[1] = make_float4(acc[4],  acc[5],  acc[6],  acc[7]);
    hp[2] = make_float4(acc[8],  acc[9],  acc[10], acc[11]);
    hp[3] = make_float4(acc[12], acc[13], acc[14], acc[15]);
    hp[4] = make_float4(acc[16], acc[17], acc[18], acc[19]);
}

// ---------- fused aggregate: LDS accumulator per 128-node bucket ----------
__global__ __launch_bounds__(256) void k_agg(const int* __restrict__ boff,
                                             const int* __restrict__ bcnt,
                                             const int* __restrict__ bpairs,
                                             const float* __restrict__ dinv,
                                             const float* __restrict__ h,
                                             const float* __restrict__ bmu,
                                             const float* __restrict__ bls,
                                             float* __restrict__ out) {
    __shared__ float acc[BNODES * ASTRIDE];
    int b = blockIdx.x, t = threadIdx.x;
    for (int i = t; i < BNODES * ASTRIDE; i += 256) acc[i] = 0.0f;
    __syncthreads();

    int start = boff[b], n = bcnt[b];
    const int* bp = bpairs + start;

#define EDGE_BODY(PK)                                                     \
    {                                                                     \
        int cl = (PK) & 127;                                              \
        int r  = ((unsigned)(PK)) >> 7;                                   \
        float s = dinv[r];                                                \
        const float4* hp = (const float4*)(h + (size_t)r * NC);           \
        float4 v0 = hp[0], v1 = hp[1], v2 = hp[2], v3 = hp[3], v4 = hp[4];\
        float* a = &acc[cl * ASTRIDE];                                    \
        atomicAdd(a + 0,  v0.x * s); atomicAdd(a + 1,  v0.y * s);         \
        atomicAdd(a + 2,  v0.z * s); atomicAdd(a + 3,  v0.w * s);         \
        atomicAdd(a + 4,  v1.x * s); atomicAdd(a + 5,  v1.y * s);         \
        atomicAdd(a + 6,  v1.z * s); atomicAdd(a + 7,  v1.w * s);         \
        atomicAdd(a + 8,  v2.x * s); atomicAdd(a + 9,  v2.y * s);         \
        atomicAdd(a + 10, v2.z * s); atomicAdd(a + 11, v2.w * s);         \
        atomicAdd(a + 12, v3.x * s); atomicAdd(a + 13, v3.y * s);         \
        atomicAdd(a + 14, v3.z * s); atomicAdd(a + 15, v3.w * s);         \
        atomicAdd(a + 16, v4.x * s); atomicAdd(a + 17, v4.y * s);         \
        atomicAdd(a + 18, v4.z * s); atomicAdd(a + 19, v4.w * s);         \
    }

    int p = t;
    for (; p + 256 < n; p += 512) {
        int pk0 = bp[p];
        int pk1 = bp[p + 256];
        EDGE_BODY(pk0);
        EDGE_BODY(pk1);
    }
    if (p < n) {
        int pk0 = bp[p];
        EDGE_BODY(pk0);
    }
#undef EDGE_BODY
    __syncthreads();

    // epilogue: out = dinv[n]*acc + dinv[n]^2*h[n] + bias ; each elem written once
    int node0 = b * BNODES;
    for (int i = t; i < BNODES * NC; i += 256) {
        int ln = i / NC, ch = i - ln * NC;
        int node = node0 + ln;
        if (node < N_NODES) {
            float dn = dinv[node];
            float hv = h[(size_t)node * NC + ch];
            float base = (ch < OC) ? bmu[ch] : bls[ch - OC];
            float val = dn * acc[ln * ASTRIDE + ch] + dn * dn * hv + base;
            size_t idx = (ch < OC) ? ((size_t)node * OC + ch)
                                   : ((size_t)N_NODES * OC + (size_t)node * OC + (ch - OC));
            out[idx] = val;
        }
    }
}

// ======================= fallback (atomic scatter path, tiny ws) =======================
__global__ __launch_bounds__(256) void k_init_deg(float* __restrict__ deg) {
    int i = blockIdx.x * 256 + threadIdx.x;
    if (i < N_NODES) deg[i] = 1.0f;
}
__global__ __launch_bounds__(256) void k_count(const int* __restrict__ col, float* __restrict__ deg) {
    int e = blockIdx.x * 256 + threadIdx.x;
    if (e < N_EDGES) atomicAdd(&deg[col[e]], 1.0f);
}
__global__ __launch_bounds__(256) void k_dinv(float* __restrict__ deg) {
    int i = blockIdx.x * 256 + threadIdx.x;
    if (i < N_NODES) deg[i] = rsqrtf(deg[i]);
}
__global__ __launch_bounds__(256) void k_scatter(const int* __restrict__ row, const int* __restrict__ col,
                                                 const float* __restrict__ dinv, const float* __restrict__ h,
                                                 float* __restrict__ out) {
    int e = blockIdx.x * 256 + threadIdx.x;
    if (e >= N_EDGES) return;
    int r = row[e], c = col[e];
    float s = dinv[r] * dinv[c];
    const float4* hp = (const float4*)(h + (size_t)r * NC);
    float4 h0 = hp[0], h1 = hp[1], h2 = hp[2], h3 = hp[3], h4 = hp[4];
    float* om = out + (size_t)c * OC;
    float* ol = om + (size_t)N_NODES * OC;
    atomicAdd(om + 0, h0.x * s); atomicAdd(om + 1, h0.y * s); atomicAdd(om + 2, h0.z * s);
    atomicAdd(om + 3, h0.w * s); atomicAdd(om + 4, h1.x * s); atomicAdd(om + 5, h1.y * s);
    atomicAdd(om + 6, h1.z * s); atomicAdd(om + 7, h1.w * s); atomicAdd(om + 8, h2.x * s);
    atomicAdd(om + 9, h2.y * s);
    atomicAdd(ol + 0, h2.z * s); atomicAdd(ol + 1, h2.w * s); atomicAdd(ol + 2, h3.x * s);
    atomicAdd(ol + 3, h3.y * s); atomicAdd(ol + 4, h3.z * s); atomicAdd(ol + 5, h3.w * s);
    atomicAdd(ol + 6, h4.x * s); atomicAdd(ol + 7, h4.y * s); atomicAdd(ol + 8, h4.z * s);
    atomicAdd(ol + 9, h4.w * s);
}
__global__ __launch_bounds__(256) void k_final(const float* __restrict__ h, const float* __restrict__ dinv,
                                               const float* __restrict__ bmu, const float* __restrict__ bls,
                                               float* __restrict__ out) {
    int i = blockIdx.x * 256 + threadIdx.x;
    if (i >= N_NODES * OC) return;
    int node = i / OC, c = i - node * OC;
    float d = dinv[node];
    float d2 = d * d;
    out[i]                += h[node * NC + c]      * d2 + bmu[c];
    out[N_NODES * OC + i] += h[node * NC + OC + c] * d2 + bls[c];
}

extern "C" void kernel_launch(void* const* d_in, const int* in_sizes, int n_in,
                              void* d_out, int out_size, void* d_ws, size_t ws_size,
                              hipStream_t stream) {
    const float* x   = (const float*)d_in[0];
    const int*   ei  = (const int*)d_in[1];
    const float* Wmu = (const float*)d_in[2];
    const float* bmu = (const float*)d_in[3];
    const float* Wls = (const float*)d_in[4];
    const float* bls = (const float*)d_in[5];
    float* out = (float*)d_out;

    const int* row = ei;            // edge_index[0] (sources)
    const int* col = ei + N_EDGES;  // edge_index[1] (targets)

    // ws layout (bucket path):
    //   bcnt  int[1024]    @ 0
    //   boff  int[1024]    @ 4K
    //   bptr  int[1024]    @ 8K
    //   dinv  f32[100096]  @ 16K     (400 KB)
    //   h     f32[N*20]    @ 512K    (8 MB)
    //   bpairs int[E]      @ 9M      (12.8 MB)
    const size_t REQ = (size_t)(9 << 20) + (size_t)N_EDGES * 4;

    if (ws_size >= REQ) {
        char* w = (char*)d_ws;
        int*   bcnt   = (int*)(w);
        int*   boff   = (int*)(w + 4096);
        int*   bptr   = (int*)(w + 8192);
        float* dinv   = (float*)(w + 16384);
        float* h      = (float*)(w + (512 << 10));
        int*   bpairs = (int*)(w + (9 << 20));

        hipMemsetAsync(bcnt, 0, NBUCK * sizeof(int), stream);
        k_chist<<<512, 256, 0, stream>>>(col, bcnt);
        k_scan<<<1, 1024, 0, stream>>>(bcnt, boff, bptr);
        k_bin<<<(N_EDGES + 255) / 256, 256, 0, stream>>>(row, col, bptr, bpairs);
        k_bcount<<<NBUCK, 256, 0, stream>>>(boff, bcnt, bpairs, dinv);
        k_gemm<<<(N_NODES + 255) / 256, 256, 0, stream>>>(x, Wmu, Wls, h);
        k_agg<<<NBUCK, 256, 0, stream>>>(boff, bcnt, bpairs, dinv, h, bmu, bls, out);
    } else {
        // fallback: atomic scatter path
        float* deg = (float*)d_ws;
        float* h   = (float*)((char*)d_ws + (1 << 20));
        hipMemsetAsync(d_out, 0, (size_t)out_size * sizeof(float), stream);
        k_init_deg<<<(N_NODES + 255) / 256, 256, 0, stream>>>(deg);
        k_count<<<(N_EDGES + 255) / 256, 256, 0, stream>>>(col, deg);
        k_dinv<<<(N_NODES + 255) / 256, 256, 0, stream>>>(deg);
        k_gemm<<<(N_NODES + 255) / 256, 256, 0, stream>>>(x, Wmu, Wls, h);
        k_scatter<<<(N_EDGES + 255) / 256, 256, 0, stream>>>(row, col, deg, h, out);
        k_final<<<(N_NODES * OC + 255) / 256, 256, 0, stream>>>(h, deg, bmu, bls, out);
    }
}

// Round 4
// 390.255 us; speedup vs baseline: 3.5471x; 3.5471x over previous
//
#include <hip/hip_runtime.h>
#include <math.h>

#define N_NODES 100000
#define N_EDGES 3200000
#define IN_CH 256
#define NC 20        // combined output channels (10 mu + 10 logstd)
#define OC 10
#define NPB 256      // nodes per bucket (col >> 8)
#define NBUCK 391    // ceil(100000/256)
#define CAP 10240    // per-bucket slot capacity: mean 8184, sigma~90 -> 22 sigma margin
#define CHUNK 16384  // edges per binning block
#define NCHUNK 196   // ceil(N_EDGES/CHUNK)

// ---------- init per-bucket allocation cursors ----------
__global__ __launch_bounds__(256) void k_initptr(int* __restrict__ bptr) {
    int i = blockIdx.x * 256 + threadIdx.x;
    if (i < NBUCK) bptr[i] = i * CAP;
}

// ---------- LDS-staged chunk binning: 1 global atomic per (bucket,chunk) ----------
__global__ __launch_bounds__(256) void k_bin2(const int* __restrict__ row,
                                              const int* __restrict__ col,
                                              int* __restrict__ bptr,
                                              int* __restrict__ bpairs) {
    __shared__ int lh[NBUCK];     // chunk-local histogram, then running pos
    __shared__ int lbase[NBUCK];  // reserved global base per bucket
    int t = threadIdx.x;
    int e0 = blockIdx.x * CHUNK;
    int nE = N_EDGES - e0; if (nE > CHUNK) nE = CHUNK;

    for (int i = t; i < NBUCK; i += 256) lh[i] = 0;
    __syncthreads();
    for (int p = t; p < nE; p += 256)
        atomicAdd(&lh[col[e0 + p] >> 8], 1);
    __syncthreads();
    for (int i = t; i < NBUCK; i += 256) {
        int c = lh[i];
        lbase[i] = c ? atomicAdd(&bptr[i], c) : 0;
        lh[i] = 0;
    }
    __syncthreads();
    for (int p = t; p < nE; p += 256) {
        int c = col[e0 + p], r = row[e0 + p];
        int bk = c >> 8;
        int q = atomicAdd(&lh[bk], 1);
        int slot = lbase[bk] + q;
        if (slot < (bk + 1) * CAP)                 // overflow guard (statistically never)
            bpairs[slot] = (r << 8) | (c & 255);
    }
}

// ---------- per-node degree via LDS counts; dinv = rsqrt(deg+1) ----------
__global__ __launch_bounds__(256) void k_bcount(const int* __restrict__ bptr,
                                                const int* __restrict__ bpairs,
                                                float* __restrict__ dinv) {
    __shared__ int lc[NPB];
    int b = blockIdx.x, t = threadIdx.x;
    lc[t] = 0;
    __syncthreads();
    int start = b * CAP;
    int n = bptr[b] - start; if (n > CAP) n = CAP;
    for (int p = t; p < n; p += 256)
        atomicAdd(&lc[bpairs[start + p] & 255], 1);
    __syncthreads();
    int node = b * NPB + t;
    if (node < N_NODES) dinv[node] = rsqrtf((float)(lc[t] + 1));  // +1 self loop
}

// ---------- fused skinny GEMM: h[N][20] = x @ [W_mu | W_logstd] ----------
// weights transposed in LDS [c][k]; wave-uniform ds_read_b128 -> broadcast, 4 FMAs per read
__global__ __launch_bounds__(256) void k_gemm(const float* __restrict__ x,
                                              const float* __restrict__ Wmu,
                                              const float* __restrict__ Wls,
                                              float* __restrict__ h) {
    __shared__ float sW[NC * IN_CH];  // sW[c*256+k]
    int t = threadIdx.x;
    for (int j = t; j < IN_CH * OC; j += 256) {
        int k = j / OC, c = j - k * OC;
        sW[c * IN_CH + k]          = Wmu[j];
        sW[(c + OC) * IN_CH + k]   = Wls[j];
    }
    __syncthreads();
    int node = blockIdx.x * 256 + t;
    if (node >= N_NODES) return;

    const float4* x4 = (const float4*)(x + (size_t)node * IN_CH);
    float acc[NC];
#pragma unroll
    for (int c = 0; c < NC; c++) acc[c] = 0.0f;

    for (int kc = 0; kc < IN_CH; kc += 16) {
        float4 xv0 = x4[kc / 4 + 0];
        float4 xv1 = x4[kc / 4 + 1];
        float4 xv2 = x4[kc / 4 + 2];
        float4 xv3 = x4[kc / 4 + 3];
#pragma unroll
        for (int c = 0; c < NC; c++) {
            const float4* wp = (const float4*)&sW[c * IN_CH + kc];  // uniform -> broadcast
            float4 w0 = wp[0], w1 = wp[1], w2 = wp[2], w3 = wp[3];
            acc[c] += xv0.x * w0.x + xv0.y * w0.y + xv0.z * w0.z + xv0.w * w0.w
                    + xv1.x * w1.x + xv1.y * w1.y + xv1.z * w1.z + xv1.w * w1.w
                    + xv2.x * w2.x + xv2.y * w2.y + xv2.z * w2.z + xv2.w * w2.w
                    + xv3.x * w3.x + xv3.y * w3.y + xv3.z * w3.z + xv3.w * w3.w;
        }
    }

    float4* hp = (float4*)(h + (size_t)node * NC);
    hp[0] = make_float4(acc[0],  acc[1],  acc[2],  acc[3]);
    hp[1] = make_float4(acc[4],  acc[5],  acc[6],  acc[7]);
    hp[2] = make_float4(acc[8],  acc[9],  acc[10], acc[11]);
    hp[3] = make_float4(acc[12], acc[13], acc[14], acc[15]);
    hp[4] = make_float4(acc[16], acc[17], acc[18], acc[19]);
}

// ---------- aggregate: LDS fine-sort, then register accumulation per node ----------
__global__ __launch_bounds__(256) void k_agg2(const int* __restrict__ bptr,
                                              const int* __restrict__ bpairs,
                                              const float* __restrict__ dinv,
                                              const float* __restrict__ h,
                                              const float* __restrict__ bmu,
                                              const float* __restrict__ bls,
                                              float* __restrict__ out) {
    __shared__ int soff[NPB];   // scan workspace
    __shared__ int spos[NPB];   // counts -> running positions
    __shared__ int ssrc[CAP];   // row ids sorted by local node
    int b = blockIdx.x, t = threadIdx.x;
    int start = b * CAP;
    int n = bptr[b] - start; if (n > CAP) n = CAP;

    spos[t] = 0;
    __syncthreads();
    for (int p = t; p < n; p += 256)
        atomicAdd(&spos[bpairs[start + p] & 255], 1);
    __syncthreads();

    int cnt = spos[t];
    soff[t] = cnt;
    __syncthreads();
    // Hillis-Steele inclusive scan over 256
    for (int o = 1; o < 256; o <<= 1) {
        int v = (t >= o) ? soff[t - o] : 0;
        __syncthreads();
        soff[t] += v;
        __syncthreads();
    }
    int excl = soff[t] - cnt;
    spos[t] = excl;
    __syncthreads();

    for (int p = t; p < n; p += 256) {
        int pk = bpairs[start + p];
        int cl = pk & 255;
        int q = atomicAdd(&spos[cl], 1);
        ssrc[q] = ((unsigned)pk) >> 8;
    }
    __syncthreads();

    // per-node register accumulation
    float a[NC];
#pragma unroll
    for (int c = 0; c < NC; c++) a[c] = 0.0f;

    int j = excl, e = excl + cnt;
    for (; j + 1 < e; j += 2) {
        int r0 = ssrc[j], r1 = ssrc[j + 1];
        float s0 = dinv[r0], s1 = dinv[r1];
        const float4* h0 = (const float4*)(h + (size_t)r0 * NC);
        const float4* h1 = (const float4*)(h + (size_t)r1 * NC);
#pragma unroll
        for (int q4 = 0; q4 < 5; q4++) {
            float4 v0 = h0[q4], v1 = h1[q4];
            a[q4 * 4 + 0] += s0 * v0.x + s1 * v1.x;
            a[q4 * 4 + 1] += s0 * v0.y + s1 * v1.y;
            a[q4 * 4 + 2] += s0 * v0.z + s1 * v1.z;
            a[q4 * 4 + 3] += s0 * v0.w + s1 * v1.w;
        }
    }
    if (j < e) {
        int r0 = ssrc[j];
        float s0 = dinv[r0];
        const float4* h0 = (const float4*)(h + (size_t)r0 * NC);
#pragma unroll
        for (int q4 = 0; q4 < 5; q4++) {
            float4 v0 = h0[q4];
            a[q4 * 4 + 0] += s0 * v0.x;
            a[q4 * 4 + 1] += s0 * v0.y;
            a[q4 * 4 + 2] += s0 * v0.z;
            a[q4 * 4 + 3] += s0 * v0.w;
        }
    }

    int node = b * NPB + t;
    if (node >= N_NODES) return;
    float dn = rsqrtf((float)(cnt + 1));
    const float* hs = h + (size_t)node * NC;
#pragma unroll
    for (int c = 0; c < NC; c++) a[c] += dn * hs[c];   // self loop
#pragma unroll
    for (int c = 0; c < OC; c++) {
        out[(size_t)node * OC + c]                        = dn * a[c]      + bmu[c];
        out[(size_t)N_NODES * OC + (size_t)node * OC + c] = dn * a[c + OC] + bls[c];
    }
}

// ======================= fallback (atomic scatter path, tiny ws) =======================
__global__ __launch_bounds__(256) void k_init_deg(float* __restrict__ deg) {
    int i = blockIdx.x * 256 + threadIdx.x;
    if (i < N_NODES) deg[i] = 1.0f;
}
__global__ __launch_bounds__(256) void k_count(const int* __restrict__ col, float* __restrict__ deg) {
    int e = blockIdx.x * 256 + threadIdx.x;
    if (e < N_EDGES) atomicAdd(&deg[col[e]], 1.0f);
}
__global__ __launch_bounds__(256) void k_dinv(float* __restrict__ deg) {
    int i = blockIdx.x * 256 + threadIdx.x;
    if (i < N_NODES) deg[i] = rsqrtf(deg[i]);
}
__global__ __launch_bounds__(256) void k_scatter(const int* __restrict__ row, const int* __restrict__ col,
                                                 const float* __restrict__ dinv, const float* __restrict__ h,
                                                 float* __restrict__ out) {
    int e = blockIdx.x * 256 + threadIdx.x;
    if (e >= N_EDGES) return;
    int r = row[e], c = col[e];
    float s = dinv[r] * dinv[c];
    const float4* hp = (const float4*)(h + (size_t)r * NC);
    float4 h0 = hp[0], h1 = hp[1], h2 = hp[2], h3 = hp[3], h4 = hp[4];
    float* om = out + (size_t)c * OC;
    float* ol = om + (size_t)N_NODES * OC;
    atomicAdd(om + 0, h0.x * s); atomicAdd(om + 1, h0.y * s); atomicAdd(om + 2, h0.z * s);
    atomicAdd(om + 3, h0.w * s); atomicAdd(om + 4, h1.x * s); atomicAdd(om + 5, h1.y * s);
    atomicAdd(om + 6, h1.z * s); atomicAdd(om + 7, h1.w * s); atomicAdd(om + 8, h2.x * s);
    atomicAdd(om + 9, h2.y * s);
    atomicAdd(ol + 0, h2.z * s); atomicAdd(ol + 1, h2.w * s); atomicAdd(ol + 2, h3.x * s);
    atomicAdd(ol + 3, h3.y * s); atomicAdd(ol + 4, h3.z * s); atomicAdd(ol + 5, h3.w * s);
    atomicAdd(ol + 6, h4.x * s); atomicAdd(ol + 7, h4.y * s); atomicAdd(ol + 8, h4.z * s);
    atomicAdd(ol + 9, h4.w * s);
}
__global__ __launch_bounds__(256) void k_final(const float* __restrict__ h, const float* __restrict__ dinv,
                                               const float* __restrict__ bmu, const float* __restrict__ bls,
                                               float* __restrict__ out) {
    int i = blockIdx.x * 256 + threadIdx.x;
    if (i >= N_NODES * OC) return;
    int node = i / OC, c = i - node * OC;
    float d = dinv[node];
    float d2 = d * d;
    out[i]                += h[node * NC + c]      * d2 + bmu[c];
    out[N_NODES * OC + i] += h[node * NC + OC + c] * d2 + bls[c];
}

extern "C" void kernel_launch(void* const* d_in, const int* in_sizes, int n_in,
                              void* d_out, int out_size, void* d_ws, size_t ws_size,
                              hipStream_t stream) {
    const float* x   = (const float*)d_in[0];
    const int*   ei  = (const int*)d_in[1];
    const float* Wmu = (const float*)d_in[2];
    const float* bmu = (const float*)d_in[3];
    const float* Wls = (const float*)d_in[4];
    const float* bls = (const float*)d_in[5];
    float* out = (float*)d_out;

    const int* row = ei;            // edge_index[0] (sources)
    const int* col = ei + N_EDGES;  // edge_index[1] (targets)

    // ws layout:
    //   bptr   int[NBUCK]        @ 0        (4 KB)
    //   dinv   f32[100096]       @ 8 KB     (400 KB)
    //   h      f32[N*20]         @ 512 KB   (8 MB)
    //   bpairs int[NBUCK*CAP]    @ 8.5 MB   (~15.3 MB)
    // total ~23.8 MB (<= 25.38 MB known-present from round-2 run)
    const size_t BPAIRS_OFF = (size_t)(8 << 20) + (512 << 10);
    const size_t REQ = BPAIRS_OFF + (size_t)NBUCK * CAP * 4;

    if (ws_size >= REQ) {
        char* w = (char*)d_ws;
        int*   bptr   = (int*)(w);
        float* dinv   = (float*)(w + 8192);
        float* h      = (float*)(w + (512 << 10));
        int*   bpairs = (int*)(w + BPAIRS_OFF);

        k_initptr<<<2, 256, 0, stream>>>(bptr);
        k_bin2<<<NCHUNK, 256, 0, stream>>>(row, col, bptr, bpairs);
        k_bcount<<<NBUCK, 256, 0, stream>>>(bptr, bpairs, dinv);
        k_gemm<<<(N_NODES + 255) / 256, 256, 0, stream>>>(x, Wmu, Wls, h);
        k_agg2<<<NBUCK, 256, 0, stream>>>(bptr, bpairs, dinv, h, bmu, bls, out);
    } else {
        // fallback: atomic scatter path
        float* deg = (float*)d_ws;
        float* h   = (float*)((char*)d_ws + (1 << 20));
        hipMemsetAsync(d_out, 0, (size_t)out_size * sizeof(float), stream);
        k_init_deg<<<(N_NODES + 255) / 256, 256, 0, stream>>>(deg);
        k_count<<<(N_EDGES + 255) / 256, 256, 0, stream>>>(col, deg);
        k_dinv<<<(N_NODES + 255) / 256, 256, 0, stream>>>(deg);
        k_gemm<<<(N_NODES + 255) / 256, 256, 0, stream>>>(x, Wmu, Wls, h);
        k_scatter<<<(N_EDGES + 255) / 256, 256, 0, stream>>>(row, col, deg, h, out);
        k_final<<<(N_NODES * OC + 255) / 256, 256, 0, stream>>>(h, deg, bmu, bls, out);
    }
}

// Round 5
// 381.708 us; speedup vs baseline: 3.6265x; 1.0224x over previous
//
#include <hip/hip_runtime.h>
#include <math.h>

#define N_NODES 100000
#define N_EDGES 3200000
#define IN_CH 256
#define NC 20        // combined output channels (10 mu + 10 logstd)
#define OC 10
#define NPB 256      // nodes per bucket (col >> 8)
#define NBUCK 391    // ceil(100000/256)
#define CAP 10240    // per-bucket slot capacity (mean 8184, ~22 sigma margin)
#define CHUNK 16384  // edges per binning block
#define NCHUNK 196   // ceil(N_EDGES/CHUNK)

// ---------- init per-bucket allocation cursors ----------
__global__ __launch_bounds__(256) void k_initptr(int* __restrict__ bptr) {
    int i = blockIdx.x * 256 + threadIdx.x;
    if (i < NBUCK) bptr[i] = i * CAP;
}

// ---------- LDS-staged chunk binning: 1 global atomic per (bucket,chunk) ----------
__global__ __launch_bounds__(256) void k_bin2(const int* __restrict__ row,
                                              const int* __restrict__ col,
                                              int* __restrict__ bptr,
                                              int* __restrict__ bpairs) {
    __shared__ int lh[NBUCK];     // chunk-local histogram, then running pos
    __shared__ int lbase[NBUCK];  // reserved global base per bucket
    int t = threadIdx.x;
    int e0 = blockIdx.x * CHUNK;
    int nE = N_EDGES - e0; if (nE > CHUNK) nE = CHUNK;

    for (int i = t; i < NBUCK; i += 256) lh[i] = 0;
    __syncthreads();
    for (int p = t; p < nE; p += 256)
        atomicAdd(&lh[col[e0 + p] >> 8], 1);
    __syncthreads();
    for (int i = t; i < NBUCK; i += 256) {
        int c = lh[i];
        lbase[i] = c ? atomicAdd(&bptr[i], c) : 0;
        lh[i] = 0;
    }
    __syncthreads();
    for (int p = t; p < nE; p += 256) {
        int c = col[e0 + p], r = row[e0 + p];
        int bk = c >> 8;
        int q = atomicAdd(&lh[bk], 1);
        int slot = lbase[bk] + q;
        if (slot < (bk + 1) * CAP)                 // overflow guard (statistically never)
            bpairs[slot] = (r << 8) | (c & 255);
    }
}

// ---------- per-bucket counting sort IN PLACE + dinv/offs/cnt ----------
__global__ __launch_bounds__(256) void k_bsort(const int* __restrict__ bptr,
                                               int* __restrict__ bpairs,
                                               float* __restrict__ dinv,
                                               int* __restrict__ offs,
                                               int* __restrict__ cntA) {
    __shared__ int lcnt[NPB];
    __shared__ int lscan[NPB];
    __shared__ int ssrc[CAP];
    int b = blockIdx.x, t = threadIdx.x;
    int start = b * CAP;
    int n = bptr[b] - start; if (n > CAP) n = CAP;

    lcnt[t] = 0;
    __syncthreads();
    for (int p = t; p < n; p += 256)
        atomicAdd(&lcnt[bpairs[start + p] & 255], 1);
    __syncthreads();
    int cnt = lcnt[t];
    lscan[t] = cnt;
    __syncthreads();
    for (int o = 1; o < 256; o <<= 1) {
        int v = (t >= o) ? lscan[t - o] : 0;
        __syncthreads();
        lscan[t] += v;
        __syncthreads();
    }
    int excl = lscan[t] - cnt;
    lcnt[t] = excl;   // reuse as running positions
    __syncthreads();
    for (int p = t; p < n; p += 256) {
        int pk = bpairs[start + p];
        int q = atomicAdd(&lcnt[pk & 255], 1);
        ssrc[q] = ((unsigned)pk) >> 8;
    }
    __syncthreads();
    for (int p = t; p < n; p += 256)           // coalesced writeback: bpairs now = sorted srcs
        bpairs[start + p] = ssrc[p];

    int node = b * NPB + t;
    if (node < N_NODES) {
        dinv[node] = rsqrtf((float)(cnt + 1));  // +1 self loop
        offs[node] = start + excl;
        cntA[node] = cnt;
    }
}

// ---------- bf16 pack helper (RNE) ----------
__device__ __forceinline__ unsigned bfpack(float a, float b) {
    unsigned ua = __float_as_uint(a), ub = __float_as_uint(b);
    ua = (ua + 0x7FFFu + ((ua >> 16) & 1u)) >> 16;
    ub = (ub + 0x7FFFu + ((ub >> 16) & 1u)) >> 16;
    return ua | (ub << 16);
}
__device__ __forceinline__ float bflo(unsigned p) { return __uint_as_float(p << 16); }
__device__ __forceinline__ float bfhi(unsigned p) { return __uint_as_float(p & 0xFFFF0000u); }

// ---------- fused skinny GEMM: h'[N][20](bf16) = dinv[n] * (x @ [W_mu|W_logstd]) ----------
// W addresses are wave-uniform -> scalar loads feed v_fmac (sgpr operand); no LDS at all.
__global__ __launch_bounds__(256) void k_gemm(const float* __restrict__ x,
                                              const float* __restrict__ Wmu,
                                              const float* __restrict__ Wls,
                                              const float* __restrict__ dinv,
                                              unsigned* __restrict__ hbf) {
    int node = blockIdx.x * 256 + threadIdx.x;
    if (node >= N_NODES) return;
    const float4* x4 = (const float4*)(x + (size_t)node * IN_CH);

    float acc[NC];
#pragma unroll
    for (int c = 0; c < NC; c++) acc[c] = 0.0f;

    for (int k4 = 0; k4 < IN_CH / 4; k4++) {
        float4 xv = x4[k4];
        float xk[4] = {xv.x, xv.y, xv.z, xv.w};
#pragma unroll
        for (int kk = 0; kk < 4; kk++) {
            const float* wm = Wmu + (k4 * 4 + kk) * OC;   // uniform -> s_load
            const float* wl = Wls + (k4 * 4 + kk) * OC;
#pragma unroll
            for (int c = 0; c < OC; c++) {
                acc[c]      += xk[kk] * wm[c];
                acc[c + OC] += xk[kk] * wl[c];
            }
        }
    }

    float d = dinv[node];
    unsigned* hp = hbf + (size_t)node * 10;   // 40B row, 8B aligned
    uint2 p01, p23;
    p01.x = bfpack(acc[0] * d,  acc[1] * d);  p01.y = bfpack(acc[2] * d,  acc[3] * d);
    p23.x = bfpack(acc[4] * d,  acc[5] * d);  p23.y = bfpack(acc[6] * d,  acc[7] * d);
    *(uint2*)(hp + 0) = p01;
    *(uint2*)(hp + 2) = p23;
    p01.x = bfpack(acc[8] * d,  acc[9] * d);  p01.y = bfpack(acc[10] * d, acc[11] * d);
    p23.x = bfpack(acc[12] * d, acc[13] * d); p23.y = bfpack(acc[14] * d, acc[15] * d);
    *(uint2*)(hp + 4) = p01;
    *(uint2*)(hp + 6) = p23;
    *(uint2*)(hp + 8) = make_uint2(bfpack(acc[16] * d, acc[17] * d),
                                   bfpack(acc[18] * d, acc[19] * d));
}

// ---------- gather reduce: 5 threads per node, zero LDS, high occupancy ----------
__global__ __launch_bounds__(256) void k_agg3(const int* __restrict__ offs,
                                              const int* __restrict__ cntA,
                                              const int* __restrict__ srcs,   // sorted bpairs
                                              const float* __restrict__ dinv,
                                              const unsigned* __restrict__ hbf,
                                              const float* __restrict__ bmu,
                                              const float* __restrict__ bls,
                                              float* __restrict__ out) {
    int gid = blockIdx.x * 256 + threadIdx.x;
    int node = gid / 5;
    int g = gid - node * 5;            // channel group: channels [4g, 4g+4)
    if (node >= N_NODES) return;
    int st = offs[node], n = cntA[node];

    float a0 = 0.f, a1 = 0.f, a2 = 0.f, a3 = 0.f;
    int j = 0;
    for (; j + 1 < n; j += 2) {
        int r0 = srcs[st + j], r1 = srcs[st + j + 1];
        uint2 p0 = *(const uint2*)(hbf + (size_t)r0 * 10 + g * 2);
        uint2 p1 = *(const uint2*)(hbf + (size_t)r1 * 10 + g * 2);
        a0 += bflo(p0.x) + bflo(p1.x);
        a1 += bfhi(p0.x) + bfhi(p1.x);
        a2 += bflo(p0.y) + bflo(p1.y);
        a3 += bfhi(p0.y) + bfhi(p1.y);
    }
    if (j < n) {
        int r0 = srcs[st + j];
        uint2 p0 = *(const uint2*)(hbf + (size_t)r0 * 10 + g * 2);
        a0 += bflo(p0.x); a1 += bfhi(p0.x); a2 += bflo(p0.y); a3 += bfhi(p0.y);
    }
    // self loop (h' already carries dinv[node])
    uint2 ps = *(const uint2*)(hbf + (size_t)node * 10 + g * 2);
    a0 += bflo(ps.x); a1 += bfhi(ps.x); a2 += bflo(ps.y); a3 += bfhi(ps.y);

    float dn = dinv[node];
    float a[4] = {a0, a1, a2, a3};
#pragma unroll
    for (int k = 0; k < 4; k++) {
        int ch = g * 4 + k;
        if (ch < OC)
            out[(size_t)node * OC + ch] = dn * a[k] + bmu[ch];
        else
            out[(size_t)N_NODES * OC + (size_t)node * OC + (ch - OC)] = dn * a[k] + bls[ch - OC];
    }
}

// ======================= fallback (atomic scatter path, tiny ws) =======================
__global__ __launch_bounds__(256) void k_init_deg(float* __restrict__ deg) {
    int i = blockIdx.x * 256 + threadIdx.x;
    if (i < N_NODES) deg[i] = 1.0f;
}
__global__ __launch_bounds__(256) void k_count(const int* __restrict__ col, float* __restrict__ deg) {
    int e = blockIdx.x * 256 + threadIdx.x;
    if (e < N_EDGES) atomicAdd(&deg[col[e]], 1.0f);
}
__global__ __launch_bounds__(256) void k_dinv(float* __restrict__ deg) {
    int i = blockIdx.x * 256 + threadIdx.x;
    if (i < N_NODES) deg[i] = rsqrtf(deg[i]);
}
__global__ __launch_bounds__(256) void k_gemm_f32(const float* __restrict__ x,
                                                  const float* __restrict__ Wmu,
                                                  const float* __restrict__ Wls,
                                                  float* __restrict__ h) {
    int node = blockIdx.x * 256 + threadIdx.x;
    if (node >= N_NODES) return;
    const float4* x4 = (const float4*)(x + (size_t)node * IN_CH);
    float acc[NC];
#pragma unroll
    for (int c = 0; c < NC; c++) acc[c] = 0.0f;
    for (int k4 = 0; k4 < IN_CH / 4; k4++) {
        float4 xv = x4[k4];
        float xk[4] = {xv.x, xv.y, xv.z, xv.w};
#pragma unroll
        for (int kk = 0; kk < 4; kk++) {
            const float* wm = Wmu + (k4 * 4 + kk) * OC;
            const float* wl = Wls + (k4 * 4 + kk) * OC;
#pragma unroll
            for (int c = 0; c < OC; c++) {
                acc[c]      += xk[kk] * wm[c];
                acc[c + OC] += xk[kk] * wl[c];
            }
        }
    }
    float* hp = h + (size_t)node * NC;
#pragma unroll
    for (int c = 0; c < NC; c++) hp[c] = acc[c];
}
__global__ __launch_bounds__(256) void k_scatter(const int* __restrict__ row, const int* __restrict__ col,
                                                 const float* __restrict__ dinv, const float* __restrict__ h,
                                                 float* __restrict__ out) {
    int e = blockIdx.x * 256 + threadIdx.x;
    if (e >= N_EDGES) return;
    int r = row[e], c = col[e];
    float s = dinv[r] * dinv[c];
    const float* hp = h + (size_t)r * NC;
    float* om = out + (size_t)c * OC;
    float* ol = om + (size_t)N_NODES * OC;
#pragma unroll
    for (int k = 0; k < OC; k++) atomicAdd(om + k, hp[k] * s);
#pragma unroll
    for (int k = 0; k < OC; k++) atomicAdd(ol + k, hp[OC + k] * s);
}
__global__ __launch_bounds__(256) void k_final(const float* __restrict__ h, const float* __restrict__ dinv,
                                               const float* __restrict__ bmu, const float* __restrict__ bls,
                                               float* __restrict__ out) {
    int i = blockIdx.x * 256 + threadIdx.x;
    if (i >= N_NODES * OC) return;
    int node = i / OC, c = i - node * OC;
    float d = dinv[node];
    float d2 = d * d;
    out[i]                += h[node * NC + c]      * d2 + bmu[c];
    out[N_NODES * OC + i] += h[node * NC + OC + c] * d2 + bls[c];
}

extern "C" void kernel_launch(void* const* d_in, const int* in_sizes, int n_in,
                              void* d_out, int out_size, void* d_ws, size_t ws_size,
                              hipStream_t stream) {
    const float* x   = (const float*)d_in[0];
    const int*   ei  = (const int*)d_in[1];
    const float* Wmu = (const float*)d_in[2];
    const float* bmu = (const float*)d_in[3];
    const float* Wls = (const float*)d_in[4];
    const float* bls = (const float*)d_in[5];
    float* out = (float*)d_out;

    const int* row = ei;            // edge_index[0] (sources)
    const int* col = ei + N_EDGES;  // edge_index[1] (targets)

    // ws layout:
    //   bptr   int[NBUCK]      @ 0       (4 KB)
    //   dinv   f32[100096]     @ 8 KB
    //   offs   int[100096]     @ 512 KB
    //   cntA   int[100096]     @ 1 MB
    //   hbf    u32[100000*10]  @ 1.5 MB  (4 MB, bf16-packed h')
    //   bpairs int[NBUCK*CAP]  @ 6 MB    (~15.3 MB; becomes sorted src list)
    // total ~21.3 MB (< 23.8 MB proven available in round 4)
    const size_t BPAIRS_OFF = (size_t)(6 << 20);
    const size_t REQ = BPAIRS_OFF + (size_t)NBUCK * CAP * 4;

    if (ws_size >= REQ) {
        char* w = (char*)d_ws;
        int*      bptr   = (int*)(w);
        float*    dinv   = (float*)(w + 8192);
        int*      offs   = (int*)(w + (512 << 10));
        int*      cntA   = (int*)(w + (1 << 20));
        unsigned* hbf    = (unsigned*)(w + (3 << 19));   // 1.5 MiB
        int*      bpairs = (int*)(w + BPAIRS_OFF);

        k_initptr<<<2, 256, 0, stream>>>(bptr);
        k_bin2<<<NCHUNK, 256, 0, stream>>>(row, col, bptr, bpairs);
        k_bsort<<<NBUCK, 256, 0, stream>>>(bptr, bpairs, dinv, offs, cntA);
        k_gemm<<<(N_NODES + 255) / 256, 256, 0, stream>>>(x, Wmu, Wls, dinv, hbf);
        k_agg3<<<(N_NODES * 5 + 255) / 256, 256, 0, stream>>>(offs, cntA, bpairs, dinv, hbf, bmu, bls, out);
    } else {
        float* deg = (float*)d_ws;
        float* h   = (float*)((char*)d_ws + (1 << 20));
        hipMemsetAsync(d_out, 0, (size_t)out_size * sizeof(float), stream);
        k_init_deg<<<(N_NODES + 255) / 256, 256, 0, stream>>>(deg);
        k_count<<<(N_EDGES + 255) / 256, 256, 0, stream>>>(col, deg);
        k_dinv<<<(N_NODES + 255) / 256, 256, 0, stream>>>(deg);
        k_gemm_f32<<<(N_NODES + 255) / 256, 256, 0, stream>>>(x, Wmu, Wls, h);
        k_scatter<<<(N_EDGES + 255) / 256, 256, 0, stream>>>(row, col, deg, h, out);
        k_final<<<(N_NODES * OC + 255) / 256, 256, 0, stream>>>(h, deg, bmu, bls, out);
    }
}

// Round 6
// 320.928 us; speedup vs baseline: 4.3133x; 1.1894x over previous
//
#include <hip/hip_runtime.h>
#include <math.h>

#define N_NODES 100000
#define N_EDGES 3200000
#define IN_CH 256
#define NC 20        // combined output channels (10 mu + 10 logstd)
#define OC 10
#define NPB 128      // nodes per bucket (col >> 7)
#define NBUCK 782    // ceil(100000/128)
#define CAP 4864     // per-bucket capacity: mean 4096, sigma ~64 -> +12 sigma
#define CHUNK 4096   // edges per binning block
#define NCHUNK 782   // ceil(N_EDGES/CHUNK)

// ---------- init per-bucket allocation cursors ----------
__global__ __launch_bounds__(256) void k_initptr(int* __restrict__ bptr) {
    int i = blockIdx.x * 256 + threadIdx.x;
    if (i < NBUCK) bptr[i] = i * CAP;
}

// ---------- LDS-staged chunk binning: 1 global atomic per (bucket,chunk) ----------
__global__ __launch_bounds__(256) void k_bin2(const int* __restrict__ row,
                                              const int* __restrict__ col,
                                              int* __restrict__ bptr,
                                              int* __restrict__ bpairs) {
    __shared__ int lh[NBUCK];     // chunk-local histogram, then running pos
    __shared__ int lbase[NBUCK];  // reserved global base per bucket
    int t = threadIdx.x;
    int e0 = blockIdx.x * CHUNK;
    int nE = N_EDGES - e0; if (nE > CHUNK) nE = CHUNK;

    for (int i = t; i < NBUCK; i += 256) lh[i] = 0;
    __syncthreads();
    for (int p = t; p < nE; p += 256)
        atomicAdd(&lh[col[e0 + p] >> 7], 1);
    __syncthreads();
    for (int i = t; i < NBUCK; i += 256) {
        int c = lh[i];
        lbase[i] = c ? atomicAdd(&bptr[i], c) : 0;
        lh[i] = 0;
    }
    __syncthreads();
    for (int p = t; p < nE; p += 256) {
        int c = col[e0 + p], r = row[e0 + p];
        int bk = c >> 7;
        int q = atomicAdd(&lh[bk], 1);
        int slot = lbase[bk] + q;
        if (slot < (bk + 1) * CAP)                 // overflow guard (statistically never)
            bpairs[slot] = (r << 7) | (c & 127);
    }
}

// ---------- per-node degree from bucket regions; dinv = rsqrt(deg+1) ----------
__global__ __launch_bounds__(256) void k_deg(const int* __restrict__ bptr,
                                             const int* __restrict__ bpairs,
                                             float* __restrict__ dinv) {
    __shared__ int lc[NPB];
    int b = blockIdx.x, t = threadIdx.x;
    if (t < NPB) lc[t] = 0;
    __syncthreads();
    int start = b * CAP;
    int n = bptr[b] - start; if (n > CAP) n = CAP;
    for (int p = t; p < n; p += 256)
        atomicAdd(&lc[bpairs[start + p] & 127], 1);
    __syncthreads();
    int node = b * NPB + t;
    if (t < NPB && node < N_NODES)
        dinv[node] = rsqrtf((float)(lc[t] + 1));   // +1 self loop
}

// ---------- bf16 pack helpers (RNE) ----------
__device__ __forceinline__ unsigned bfpack(float a, float b) {
    unsigned ua = __float_as_uint(a), ub = __float_as_uint(b);
    ua = (ua + 0x7FFFu + ((ua >> 16) & 1u)) >> 16;
    ub = (ub + 0x7FFFu + ((ub >> 16) & 1u)) >> 16;
    return ua | (ub << 16);
}
__device__ __forceinline__ float bflo(unsigned p) { return __uint_as_float(p << 16); }
__device__ __forceinline__ float bfhi(unsigned p) { return __uint_as_float(p & 0xFFFF0000u); }

// ---------- skinny GEMM, 4 threads per node (k-split), LDS W with bank swizzle ----------
// sW[c][kk][j]: idx = c*272 + kk*68 + j  (kk groups land on disjoint bank quads)
__global__ __launch_bounds__(256) void k_gemm2(const float* __restrict__ x,
                                               const float* __restrict__ Wmu,
                                               const float* __restrict__ Wls,
                                               const float* __restrict__ dinv,
                                               unsigned* __restrict__ hbf) {
    __shared__ float sW[NC * 272];
    int t = threadIdx.x;
    for (int idx = t; idx < IN_CH * OC; idx += 256) {
        int k = idx / OC, c = idx - k * OC;
        int kk = k >> 6, j = k & 63;
        sW[c * 272 + kk * 68 + j]          = Wmu[idx];
        sW[(c + OC) * 272 + kk * 68 + j]   = Wls[idx];
    }
    __syncthreads();

    int node = blockIdx.x * 64 + (t >> 2);
    int kk = t & 3;
    if (node >= N_NODES) return;

    const float4* x4 = (const float4*)(x + (size_t)node * IN_CH);
    float acc[NC];
#pragma unroll
    for (int c = 0; c < NC; c++) acc[c] = 0.0f;

#pragma unroll 4
    for (int j4 = 0; j4 < 16; j4++) {
        float4 xv = x4[kk * 16 + j4];
#pragma unroll
        for (int c = 0; c < NC; c++) {
            float4 w = *(const float4*)&sW[c * 272 + kk * 68 + j4 * 4];
            acc[c] += xv.x * w.x + xv.y * w.y + xv.z * w.z + xv.w * w.w;
        }
    }

    // quad reduction (lanes node*4+kk, quads lane-aligned)
#pragma unroll
    for (int c = 0; c < NC; c++) {
        acc[c] += __shfl_xor(acc[c], 2);
        acc[c] += __shfl_xor(acc[c], 1);
    }

    if (kk == 0) {
        float d = dinv[node];
        unsigned* hp = hbf + (size_t)node * 10;
        *(uint2*)(hp + 0) = make_uint2(bfpack(acc[0] * d,  acc[1] * d),
                                       bfpack(acc[2] * d,  acc[3] * d));
        *(uint2*)(hp + 2) = make_uint2(bfpack(acc[4] * d,  acc[5] * d),
                                       bfpack(acc[6] * d,  acc[7] * d));
        *(uint2*)(hp + 4) = make_uint2(bfpack(acc[8] * d,  acc[9] * d),
                                       bfpack(acc[10] * d, acc[11] * d));
        *(uint2*)(hp + 6) = make_uint2(bfpack(acc[12] * d, acc[13] * d),
                                       bfpack(acc[14] * d, acc[15] * d));
        *(uint2*)(hp + 8) = make_uint2(bfpack(acc[16] * d, acc[17] * d),
                                       bfpack(acc[18] * d, acc[19] * d));
    }
}

// ---------- fused sort+reduce per 128-node bucket ----------
__global__ __launch_bounds__(256) void k_agg4(const int* __restrict__ bptr,
                                              const int* __restrict__ bpairs,
                                              const unsigned* __restrict__ hbf,
                                              const float* __restrict__ bmu,
                                              const float* __restrict__ bls,
                                              float* __restrict__ out) {
    __shared__ int lcnt[NPB];    // hist -> cursor
    __shared__ int lscan[NPB];   // inclusive scan
    __shared__ int sCnt[NPB];    // per-node count
    __shared__ int ssrc[CAP];    // node-sorted src ids
    int b = blockIdx.x, t = threadIdx.x;
    int start = b * CAP;
    int n = bptr[b] - start; if (n > CAP) n = CAP;

    if (t < NPB) lcnt[t] = 0;
    __syncthreads();
    for (int p = t; p < n; p += 256)
        atomicAdd(&lcnt[bpairs[start + p] & 127], 1);
    __syncthreads();

    int cnt = 0;
    if (t < NPB) { cnt = lcnt[t]; lscan[t] = cnt; sCnt[t] = cnt; }
    __syncthreads();
    for (int o = 1; o < NPB; o <<= 1) {
        int add = 0;
        if (t < NPB && t >= o) add = lscan[t - o];
        __syncthreads();
        if (t < NPB) lscan[t] += add;
        __syncthreads();
    }
    if (t < NPB) lcnt[t] = lscan[t] - cnt;   // cursor = exclusive
    __syncthreads();

    for (int p = t; p < n; p += 256) {
        int pk = bpairs[start + p];
        int q = atomicAdd(&lcnt[pk & 127], 1);
        ssrc[q] = ((unsigned)pk) >> 7;
    }
    __syncthreads();

    // reduce: 2 threads per node, edge-split halves, shuffle combine
    int nl = t >> 1, half = t & 1;
    int node = b * NPB + nl;
    int ccnt = sCnt[nl];
    int base = lscan[nl] - ccnt;
    int mid = ccnt >> 1;
    int j0 = half ? mid : 0;
    int j1 = half ? ccnt : mid;

    float a[NC];
#pragma unroll
    for (int c = 0; c < NC; c++) a[c] = 0.0f;

#define ADDROW(R)                                                        \
    {                                                                    \
        const unsigned* hp_ = hbf + (size_t)(R) * 10;                    \
        uint2 q0 = *(const uint2*)(hp_ + 0);                             \
        uint2 q1 = *(const uint2*)(hp_ + 2);                             \
        uint2 q2 = *(const uint2*)(hp_ + 4);                             \
        uint2 q3 = *(const uint2*)(hp_ + 6);                             \
        uint2 q4 = *(const uint2*)(hp_ + 8);                             \
        a[0]  += bflo(q0.x); a[1]  += bfhi(q0.x);                        \
        a[2]  += bflo(q0.y); a[3]  += bfhi(q0.y);                        \
        a[4]  += bflo(q1.x); a[5]  += bfhi(q1.x);                        \
        a[6]  += bflo(q1.y); a[7]  += bfhi(q1.y);                        \
        a[8]  += bflo(q2.x); a[9]  += bfhi(q2.x);                        \
        a[10] += bflo(q2.y); a[11] += bfhi(q2.y);                        \
        a[12] += bflo(q3.x); a[13] += bfhi(q3.x);                        \
        a[14] += bflo(q3.y); a[15] += bfhi(q3.y);                        \
        a[16] += bflo(q4.x); a[17] += bfhi(q4.x);                        \
        a[18] += bflo(q4.y); a[19] += bfhi(q4.y);                        \
    }

    int j = j0;
    for (; j + 1 < j1; j += 2) {
        int r0 = ssrc[base + j];
        int r1 = ssrc[base + j + 1];
        ADDROW(r0);
        ADDROW(r1);
    }
    if (j < j1) {
        int r0 = ssrc[base + j];
        ADDROW(r0);
    }
    // self loop (h' already carries dinv[node]) on the even-half thread
    if (half == 0 && node < N_NODES) ADDROW(node);
#undef ADDROW

#pragma unroll
    for (int c = 0; c < NC; c++) a[c] += __shfl_xor(a[c], 1);

    if (half == 0 && node < N_NODES) {
        float dn = rsqrtf((float)(ccnt + 1));
        float* om = out + (size_t)node * OC;
        float* ol = out + (size_t)N_NODES * OC + (size_t)node * OC;
#pragma unroll
        for (int c = 0; c < OC; c++) {
            om[c] = dn * a[c]      + bmu[c];
            ol[c] = dn * a[c + OC] + bls[c];
        }
    }
}

// ======================= fallback (atomic scatter path, tiny ws) =======================
__global__ __launch_bounds__(256) void k_init_deg(float* __restrict__ deg) {
    int i = blockIdx.x * 256 + threadIdx.x;
    if (i < N_NODES) deg[i] = 1.0f;
}
__global__ __launch_bounds__(256) void k_count(const int* __restrict__ col, float* __restrict__ deg) {
    int e = blockIdx.x * 256 + threadIdx.x;
    if (e < N_EDGES) atomicAdd(&deg[col[e]], 1.0f);
}
__global__ __launch_bounds__(256) void k_dinvk(float* __restrict__ deg) {
    int i = blockIdx.x * 256 + threadIdx.x;
    if (i < N_NODES) deg[i] = rsqrtf(deg[i]);
}
__global__ __launch_bounds__(256) void k_gemm_f32(const float* __restrict__ x,
                                                  const float* __restrict__ Wmu,
                                                  const float* __restrict__ Wls,
                                                  float* __restrict__ h) {
    int node = blockIdx.x * 256 + threadIdx.x;
    if (node >= N_NODES) return;
    const float4* x4 = (const float4*)(x + (size_t)node * IN_CH);
    float acc[NC];
#pragma unroll
    for (int c = 0; c < NC; c++) acc[c] = 0.0f;
    for (int k4 = 0; k4 < IN_CH / 4; k4++) {
        float4 xv = x4[k4];
        float xk[4] = {xv.x, xv.y, xv.z, xv.w};
#pragma unroll
        for (int kk = 0; kk < 4; kk++) {
            const float* wm = Wmu + (k4 * 4 + kk) * OC;
            const float* wl = Wls + (k4 * 4 + kk) * OC;
#pragma unroll
            for (int c = 0; c < OC; c++) {
                acc[c]      += xk[kk] * wm[c];
                acc[c + OC] += xk[kk] * wl[c];
            }
        }
    }
    float* hp = h + (size_t)node * NC;
#pragma unroll
    for (int c = 0; c < NC; c++) hp[c] = acc[c];
}
__global__ __launch_bounds__(256) void k_scatter(const int* __restrict__ row, const int* __restrict__ col,
                                                 const float* __restrict__ dinv, const float* __restrict__ h,
                                                 float* __restrict__ out) {
    int e = blockIdx.x * 256 + threadIdx.x;
    if (e >= N_EDGES) return;
    int r = row[e], c = col[e];
    float s = dinv[r] * dinv[c];
    const float* hp = h + (size_t)r * NC;
    float* om = out + (size_t)c * OC;
    float* ol = om + (size_t)N_NODES * OC;
#pragma unroll
    for (int k = 0; k < OC; k++) atomicAdd(om + k, hp[k] * s);
#pragma unroll
    for (int k = 0; k < OC; k++) atomicAdd(ol + k, hp[OC + k] * s);
}
__global__ __launch_bounds__(256) void k_final(const float* __restrict__ h, const float* __restrict__ dinv,
                                               const float* __restrict__ bmu, const float* __restrict__ bls,
                                               float* __restrict__ out) {
    int i = blockIdx.x * 256 + threadIdx.x;
    if (i >= N_NODES * OC) return;
    int node = i / OC, c = i - node * OC;
    float d = dinv[node];
    float d2 = d * d;
    out[i]                += h[node * NC + c]      * d2 + bmu[c];
    out[N_NODES * OC + i] += h[node * NC + OC + c] * d2 + bls[c];
}

extern "C" void kernel_launch(void* const* d_in, const int* in_sizes, int n_in,
                              void* d_out, int out_size, void* d_ws, size_t ws_size,
                              hipStream_t stream) {
    const float* x   = (const float*)d_in[0];
    const int*   ei  = (const int*)d_in[1];
    const float* Wmu = (const float*)d_in[2];
    const float* bmu = (const float*)d_in[3];
    const float* Wls = (const float*)d_in[4];
    const float* bls = (const float*)d_in[5];
    float* out = (float*)d_out;

    const int* row = ei;            // edge_index[0] (sources)
    const int* col = ei + N_EDGES;  // edge_index[1] (targets)

    // ws layout:
    //   bptr   int[NBUCK]      @ 0       (3.1 KB)
    //   dinv   f32[100096]     @ 8 KB    (400 KB)
    //   hbf    u32[100000*10]  @ 512 KB  (4 MB, bf16-packed dinv-prescaled h)
    //   bpairs int[NBUCK*CAP]  @ 4.5 MB  (15.2 MB; packed (row<<7)|(col&127))
    // total ~19.7 MB (< 21.3 MB proven available in round 5)
    const size_t BPAIRS_OFF = (size_t)(9 << 19);   // 4.5 MiB
    const size_t REQ = BPAIRS_OFF + (size_t)NBUCK * CAP * 4;

    if (ws_size >= REQ) {
        char* w = (char*)d_ws;
        int*      bptr   = (int*)(w);
        float*    dinv   = (float*)(w + 8192);
        unsigned* hbf    = (unsigned*)(w + (512 << 10));
        int*      bpairs = (int*)(w + BPAIRS_OFF);

        k_initptr<<<(NBUCK + 255) / 256, 256, 0, stream>>>(bptr);
        k_bin2<<<NCHUNK, 256, 0, stream>>>(row, col, bptr, bpairs);
        k_deg<<<NBUCK, 256, 0, stream>>>(bptr, bpairs, dinv);
        k_gemm2<<<(N_NODES + 63) / 64, 256, 0, stream>>>(x, Wmu, Wls, dinv, hbf);
        k_agg4<<<NBUCK, 256, 0, stream>>>(bptr, bpairs, hbf, bmu, bls, out);
    } else {
        float* deg = (float*)d_ws;
        float* h   = (float*)((char*)d_ws + (1 << 20));
        hipMemsetAsync(d_out, 0, (size_t)out_size * sizeof(float), stream);
        k_init_deg<<<(N_NODES + 255) / 256, 256, 0, stream>>>(deg);
        k_count<<<(N_EDGES + 255) / 256, 256, 0, stream>>>(col, deg);
        k_dinvk<<<(N_NODES + 255) / 256, 256, 0, stream>>>(deg);
        k_gemm_f32<<<(N_NODES + 255) / 256, 256, 0, stream>>>(x, Wmu, Wls, h);
        k_scatter<<<(N_EDGES + 255) / 256, 256, 0, stream>>>(row, col, deg, h, out);
        k_final<<<(N_NODES * OC + 255) / 256, 256, 0, stream>>>(h, deg, bmu, bls, out);
    }
}